// Round 1
// baseline (181.323 us; speedup 1.0000x reference)
//
#include <hip/hip_runtime.h>

#define B_   4
#define NQ_  1024
#define NK_  1024
#define H_   8
#define HD_  64
#define DM_  512
#define SCALE_ 0.125f

typedef __attribute__((ext_vector_type(8))) short  short8;
typedef __attribute__((ext_vector_type(4))) float  f32x4;
typedef __attribute__((ext_vector_type(4))) int    i32x4;

static __device__ __forceinline__ unsigned short f2bf(float f) {
    unsigned int u = __builtin_bit_cast(unsigned int, f);
    u += 0x7FFF + ((u >> 16) & 1);
    return (unsigned short)(u >> 16);
}

// ---------------------------------------------------------------------------
// GEMM: C_bf16[M,N] = A_f32[M,K] * B_f32[K,N]   (64x64 tile, BK=32, 4 waves)
// ---------------------------------------------------------------------------
__global__ __launch_bounds__(256) void gemm_f32_bf16(
    const float* __restrict__ A, const float* __restrict__ Bw,
    unsigned short* __restrict__ C, int M, int N, int K)
{
    const int tid  = threadIdx.x;
    const int lane = tid & 63;
    const int wave = tid >> 6;
    const int m0 = blockIdx.y * 64;
    const int n0 = blockIdx.x * 64;

    __shared__ unsigned short As[64][48];   // row stride 96B (16B aligned)
    __shared__ unsigned short Bs[64][48];   // stored transposed: Bs[n][k]

    const int wr = (wave >> 1) * 32;
    const int wc = (wave & 1) * 32;

    f32x4 acc[2][2] = {};

    for (int k0 = 0; k0 < K; k0 += 32) {
        // stage A: 64 rows x 32 k  (512 float4 slots)
        #pragma unroll
        for (int i = 0; i < 2; ++i) {
            int s = tid + i * 256;
            int r = s >> 3, c4 = (s & 7) * 4;
            float4 v = *(const float4*)&A[(size_t)(m0 + r) * K + k0 + c4];
            unsigned long long p =
                 (unsigned long long)f2bf(v.x)
               | ((unsigned long long)f2bf(v.y) << 16)
               | ((unsigned long long)f2bf(v.z) << 32)
               | ((unsigned long long)f2bf(v.w) << 48);
            *(unsigned long long*)&As[r][c4] = p;
        }
        // stage B transposed: Bs[n][k]  <- Bw[k0+kk][n0+n]
        #pragma unroll
        for (int i = 0; i < 2; ++i) {
            int s = tid + i * 256;
            int kk = s >> 4, n4 = (s & 15) * 4;
            float4 v = *(const float4*)&Bw[(size_t)(k0 + kk) * N + n0 + n4];
            Bs[n4 + 0][kk] = f2bf(v.x);
            Bs[n4 + 1][kk] = f2bf(v.y);
            Bs[n4 + 2][kk] = f2bf(v.z);
            Bs[n4 + 3][kk] = f2bf(v.w);
        }
        __syncthreads();

        short8 af[2], bfr[2];
        #pragma unroll
        for (int t = 0; t < 2; ++t)
            af[t]  = *(const short8*)&As[wr + t * 16 + (lane & 15)][(lane >> 4) * 8];
        #pragma unroll
        for (int t = 0; t < 2; ++t)
            bfr[t] = *(const short8*)&Bs[wc + t * 16 + (lane & 15)][(lane >> 4) * 8];
        #pragma unroll
        for (int rt = 0; rt < 2; ++rt)
            #pragma unroll
            for (int ct = 0; ct < 2; ++ct)
                acc[rt][ct] = __builtin_amdgcn_mfma_f32_16x16x32_bf16(
                    af[rt], bfr[ct], acc[rt][ct], 0, 0, 0);
        __syncthreads();
    }

    #pragma unroll
    for (int rt = 0; rt < 2; ++rt)
      #pragma unroll
      for (int ct = 0; ct < 2; ++ct)
        #pragma unroll
        for (int r = 0; r < 4; ++r) {
            int row = m0 + wr + rt * 16 + (lane >> 4) * 4 + r;
            int col = n0 + wc + ct * 16 + (lane & 15);
            C[(size_t)row * N + col] = f2bf(acc[rt][ct][r]);
        }
}

// ---------------------------------------------------------------------------
// GEMM: out_f32[M,N] = A_bf16[M,K] * B_f32[K,N] + bias[N]
// ---------------------------------------------------------------------------
__global__ __launch_bounds__(256) void gemm_proj(
    const unsigned short* __restrict__ A, const float* __restrict__ Bw,
    const float* __restrict__ bias, float* __restrict__ C, int M, int N, int K)
{
    const int tid  = threadIdx.x;
    const int lane = tid & 63;
    const int wave = tid >> 6;
    const int m0 = blockIdx.y * 64;
    const int n0 = blockIdx.x * 64;

    __shared__ unsigned short As[64][48];
    __shared__ unsigned short Bs[64][48];

    const int wr = (wave >> 1) * 32;
    const int wc = (wave & 1) * 32;

    f32x4 acc[2][2] = {};

    for (int k0 = 0; k0 < K; k0 += 32) {
        // stage A (bf16 source): 64 rows x 32 k, 256 slots of 8
        {
            int r = tid >> 2, c8 = (tid & 3) * 8;
            *(i32x4*)&As[r][c8] = *(const i32x4*)&A[(size_t)(m0 + r) * K + k0 + c8];
        }
        #pragma unroll
        for (int i = 0; i < 2; ++i) {
            int s = tid + i * 256;
            int kk = s >> 4, n4 = (s & 15) * 4;
            float4 v = *(const float4*)&Bw[(size_t)(k0 + kk) * N + n0 + n4];
            Bs[n4 + 0][kk] = f2bf(v.x);
            Bs[n4 + 1][kk] = f2bf(v.y);
            Bs[n4 + 2][kk] = f2bf(v.z);
            Bs[n4 + 3][kk] = f2bf(v.w);
        }
        __syncthreads();

        short8 af[2], bfr[2];
        #pragma unroll
        for (int t = 0; t < 2; ++t)
            af[t]  = *(const short8*)&As[wr + t * 16 + (lane & 15)][(lane >> 4) * 8];
        #pragma unroll
        for (int t = 0; t < 2; ++t)
            bfr[t] = *(const short8*)&Bs[wc + t * 16 + (lane & 15)][(lane >> 4) * 8];
        #pragma unroll
        for (int rt = 0; rt < 2; ++rt)
            #pragma unroll
            for (int ct = 0; ct < 2; ++ct)
                acc[rt][ct] = __builtin_amdgcn_mfma_f32_16x16x32_bf16(
                    af[rt], bfr[ct], acc[rt][ct], 0, 0, 0);
        __syncthreads();
    }

    #pragma unroll
    for (int rt = 0; rt < 2; ++rt)
      #pragma unroll
      for (int ct = 0; ct < 2; ++ct)
        #pragma unroll
        for (int r = 0; r < 4; ++r) {
            int row = m0 + wr + rt * 16 + (lane >> 4) * 4 + r;
            int col = n0 + wc + ct * 16 + (lane & 15);
            C[(size_t)row * N + col] = acc[rt][ct][r] + bias[col];
        }
}

// ---------------------------------------------------------------------------
// V transpose: KVb[b*NK+nk][512 + h*64 + d]  ->  Vt[(b*H+h)*64 + d][nk]
// ---------------------------------------------------------------------------
__global__ __launch_bounds__(256) void vtrans(
    const unsigned short* __restrict__ KV, unsigned short* __restrict__ Vt)
{
    const int b = blockIdx.z, h = blockIdx.y, t0 = blockIdx.x * 64;
    __shared__ unsigned short T[64][72];
    const int tid = threadIdx.x;

    #pragma unroll
    for (int i = 0; i < 2; ++i) {
        int s = tid + i * 256;
        int r = s >> 3, c8 = (s & 7) * 8;
        *(i32x4*)&T[r][c8] =
            *(const i32x4*)&KV[(size_t)(b * NK_ + t0 + r) * 1024 + 512 + h * 64 + c8];
    }
    __syncthreads();
    #pragma unroll
    for (int i = 0; i < 2; ++i) {
        int s = tid + i * 256;
        int d = s >> 3, r8 = (s & 7) * 8;
        union { unsigned short u[8]; i32x4 v; } tmp;
        #pragma unroll
        for (int j = 0; j < 8; ++j) tmp.u[j] = T[r8 + j][d];
        *(i32x4*)&Vt[(size_t)((b * H_ + h) * 64 + d) * NK_ + t0 + r8] = tmp.v;
    }
}

// ---------------------------------------------------------------------------
// Attention: per block = one (b,h) and 16 q-rows.
//   Phase 1: S = Q K^T * scale  (fp32 in LDS, 64KB)
//   Phase 2: full-row softmax, write attn (fp32, coalesced), P bf16 in-place
//            (XOR-swizzled for conflict-free PV ds_read_b128)
//   Phase 3: O = P V  via MFMA, V read from per-head transposed Vt
// ---------------------------------------------------------------------------
__global__ __launch_bounds__(256) void attn_kernel(
    const unsigned short* __restrict__ Qb,   // [B*NQ][512]
    const unsigned short* __restrict__ KVb,  // [B*NK][1024]  (K cols 0..511)
    const unsigned short* __restrict__ Vt,   // [(B*H)*64][NK]
    float* __restrict__ attnOut,             // [B*H][NQ][NK]
    unsigned short* __restrict__ Ob)         // [B*NQ][512]
{
    const int tid  = threadIdx.x;
    const int lane = tid & 63;
    const int wave = tid >> 6;
    const int b = blockIdx.z, h = blockIdx.y;
    const int q0 = blockIdx.x * 16;

    __shared__ float S[16][1024];            // 64 KB; P bf16 reuses it in-place

    // ---- Phase 1: S = Q K^T * SCALE ----
    short8 aq[2];
    #pragma unroll
    for (int ks = 0; ks < 2; ++ks)
        aq[ks] = *(const short8*)
            &Qb[(size_t)(b * NQ_ + q0 + (lane & 15)) * 512 + h * 64 + ks * 32 + (lane >> 4) * 8];

    #pragma unroll 4
    for (int ct = 0; ct < 16; ++ct) {
        int key = wave * 256 + ct * 16 + (lane & 15);
        const unsigned short* kptr =
            &KVb[(size_t)(b * NK_ + key) * 1024 + h * 64 + (lane >> 4) * 8];
        short8 bk0 = *(const short8*)kptr;
        short8 bk1 = *(const short8*)(kptr + 32);
        f32x4 acc = {};
        acc = __builtin_amdgcn_mfma_f32_16x16x32_bf16(aq[0], bk0, acc, 0, 0, 0);
        acc = __builtin_amdgcn_mfma_f32_16x16x32_bf16(aq[1], bk1, acc, 0, 0, 0);
        #pragma unroll
        for (int r = 0; r < 4; ++r)
            S[(lane >> 4) * 4 + r][key] = acc[r] * SCALE_;
    }
    __syncthreads();

    // ---- Phase 2: softmax over each full row; wave owns rows 4w..4w+3 ----
    const size_t attnBase = ((size_t)(b * H_ + h) * NQ_ + q0) * NK_;
    #pragma unroll
    for (int i = 0; i < 4; ++i) {
        int r = wave * 4 + i;
        float v[16];
        #pragma unroll
        for (int j = 0; j < 16; ++j) v[j] = S[r][lane + 64 * j];
        float m = v[0];
        #pragma unroll
        for (int j = 1; j < 16; ++j) m = fmaxf(m, v[j]);
        #pragma unroll
        for (int off = 32; off > 0; off >>= 1) m = fmaxf(m, __shfl_xor(m, off));
        float s = 0.f;
        #pragma unroll
        for (int j = 0; j < 16; ++j) { v[j] = __expf(v[j] - m); s += v[j]; }
        #pragma unroll
        for (int off = 32; off > 0; off >>= 1) s += __shfl_xor(s, off);
        float inv = 1.0f / s;
        #pragma unroll
        for (int j = 0; j < 16; ++j) {
            float p = v[j] * inv;
            int c = lane + 64 * j;
            attnOut[attnBase + (size_t)r * NK_ + c] = p;
            unsigned int byte = (unsigned int)(r * 4096)
                              + (((unsigned int)(c * 2)) ^ ((unsigned int)(r & 7) << 4));
            *(unsigned short*)((char*)&S[0][0] + byte) = f2bf(p);
        }
    }
    __syncthreads();

    // ---- Phase 3: O[16,64] = P[16,1024] * V[1024,64]; wave owns 16 d-cols ----
    {
        const int dt = wave;
        const int row = lane & 15;
        f32x4 acc0 = {}, acc1 = {};
        const unsigned short* vbase =
            &Vt[(size_t)((b * H_ + h) * 64 + dt * 16 + (lane & 15)) * NK_ + (lane >> 4) * 8];
        #pragma unroll 4
        for (int kb = 0; kb < 1024; kb += 64) {
            unsigned int off0 = (unsigned int)((kb + (lane >> 4) * 8) * 2);
            unsigned int off1 = (unsigned int)((kb + 32 + (lane >> 4) * 8) * 2);
            unsigned int sw   = ((unsigned int)(row & 7) << 4);
            short8 pa0 = *(const short8*)((const char*)&S[0][0] + row * 4096 + (off0 ^ sw));
            short8 pa1 = *(const short8*)((const char*)&S[0][0] + row * 4096 + (off1 ^ sw));
            short8 vb0 = *(const short8*)(vbase + kb);
            short8 vb1 = *(const short8*)(vbase + kb + 32);
            acc0 = __builtin_amdgcn_mfma_f32_16x16x32_bf16(pa0, vb0, acc0, 0, 0, 0);
            acc1 = __builtin_amdgcn_mfma_f32_16x16x32_bf16(pa1, vb1, acc1, 0, 0, 0);
        }
        #pragma unroll
        for (int r = 0; r < 4; ++r) {
            float o = acc0[r] + acc1[r];
            int row_o = q0 + (lane >> 4) * 4 + r;
            int col_o = h * 64 + dt * 16 + (lane & 15);
            Ob[(size_t)(b * NQ_ + row_o) * 512 + col_o] = f2bf(o);
        }
    }
}

// ---------------------------------------------------------------------------
extern "C" void kernel_launch(void* const* d_in, const int* in_sizes, int n_in,
                              void* d_out, int out_size, void* d_ws, size_t ws_size,
                              hipStream_t stream)
{
    (void)in_sizes; (void)n_in; (void)out_size; (void)ws_size;
    const float* x    = (const float*)d_in[0];
    const float* x_q  = (const float*)d_in[1];
    const float* w_q  = (const float*)d_in[2];
    const float* w_kv = (const float*)d_in[3];
    const float* w_p  = (const float*)d_in[4];
    const float* b_p  = (const float*)d_in[5];

    float* out   = (float*)d_out;
    float* attnO = out + (size_t)B_ * NQ_ * DM_;          // 2,097,152 floats in

    unsigned short* Qb  = (unsigned short*)d_ws;           //  4 MB
    unsigned short* KVb = Qb  + (size_t)B_ * NQ_ * DM_;    //  8 MB
    unsigned short* Vt  = KVb + (size_t)B_ * NK_ * 1024;   //  4 MB
    unsigned short* Ob  = Vt  + (size_t)B_ * H_ * 64 * NK_;//  4 MB

    // Q = x_q @ w_q            [4096,512]x[512,512]
    gemm_f32_bf16<<<dim3(DM_ / 64, (B_ * NQ_) / 64), 256, 0, stream>>>(
        x_q, w_q, Qb, B_ * NQ_, DM_, DM_);
    // KV = x @ w_kv            [4096,512]x[512,1024]
    gemm_f32_bf16<<<dim3(1024 / 64, (B_ * NK_) / 64), 256, 0, stream>>>(
        x, w_kv, KVb, B_ * NK_, 1024, DM_);
    // V transpose per head
    vtrans<<<dim3(NK_ / 64, H_, B_), 256, 0, stream>>>(KVb, Vt);
    // attention
    attn_kernel<<<dim3(NQ_ / 16, H_, B_), 256, 0, stream>>>(Qb, KVb, Vt, attnO, Ob);
    // out = O @ w_proj + b
    gemm_proj<<<dim3(DM_ / 64, (B_ * NQ_) / 64), 256, 0, stream>>>(
        Ob, w_p, b_p, out, B_ * NQ_, DM_, DM_);
}

// Round 2
// 124.041 us; speedup vs baseline: 1.4618x; 1.4618x over previous
//
#include <hip/hip_runtime.h>

#define B_   4
#define NQ_  1024
#define NK_  1024
#define H_   8
#define DM_  512

typedef unsigned short us;
typedef unsigned long long ull;
typedef __attribute__((ext_vector_type(8))) short  short8;
typedef __attribute__((ext_vector_type(4))) float  f32x4;
typedef __attribute__((ext_vector_type(4))) int    i32x4;

static __device__ __forceinline__ us f2bf(float f) {
    unsigned int u = __builtin_bit_cast(unsigned int, f);
    u += 0x7FFF + ((u >> 16) & 1);
    return (us)(u >> 16);
}

// ---------------------------------------------------------------------------
// Weight convert+transpose: W_f32[K][N] -> Wt_bf16[N][K].  256 blocks.
// ---------------------------------------------------------------------------
__global__ __launch_bounds__(256) void wtrans(
    const float* __restrict__ wq, const float* __restrict__ wkv,
    const float* __restrict__ wp,
    us* __restrict__ Wq_t, us* __restrict__ Wkv_t, us* __restrict__ Wp_t)
{
    const int bx = blockIdx.x;
    const float* src; us* dst; int k0, n0, N; const int K = 512;
    if (bx < 64)       { src = wq;  dst = Wq_t;  N = 512;  int t = bx;       k0 = (t >> 3) * 64; n0 = (t & 7) * 64; }
    else if (bx < 192) { src = wkv; dst = Wkv_t; N = 1024; int t = bx - 64;  k0 = (t >> 4) * 64; n0 = (t & 15) * 64; }
    else               { src = wp;  dst = Wp_t;  N = 512;  int t = bx - 192; k0 = (t >> 3) * 64; n0 = (t & 7) * 64; }

    __shared__ us T[64][72];
    const int tid = threadIdx.x;
    #pragma unroll
    for (int i = 0; i < 4; ++i) {
        int s = tid + i * 256;
        int r = s >> 4, c4 = (s & 15) * 4;
        float4 v = *(const float4*)&src[(size_t)(k0 + r) * N + n0 + c4];
        T[r][c4 + 0] = f2bf(v.x); T[r][c4 + 1] = f2bf(v.y);
        T[r][c4 + 2] = f2bf(v.z); T[r][c4 + 3] = f2bf(v.w);
    }
    __syncthreads();
    #pragma unroll
    for (int i = 0; i < 2; ++i) {
        int s = tid + i * 256;
        int n = s >> 3, k8 = (s & 7) * 8;
        union { us u[8]; i32x4 v; } tmp;
        #pragma unroll
        for (int j = 0; j < 8; ++j) tmp.u[j] = T[k8 + j][n];
        *(i32x4*)&dst[(size_t)(n0 + n) * K + k0 + k8] = tmp.v;
    }
}

// ---------------------------------------------------------------------------
// Shared GEMM pieces: 64x64 tile, BK=64, linear LDS [64][64] with XOR slot
// swizzle (slot^ = slot ^ (row&7)) so ds_read_b128 fragments are conflict-free.
// ---------------------------------------------------------------------------
__device__ __forceinline__ void stageA_f32(const float* A, us* As, int m0, int k0, int K, int tid) {
    #pragma unroll
    for (int i = 0; i < 2; ++i) {
        int s = tid + i * 256;
        int row = s >> 3, slot = s & 7;
        const float* p = &A[(size_t)(m0 + row) * K + k0 + slot * 8];
        float4 a = *(const float4*)p, b = *(const float4*)(p + 4);
        union { us u[8]; i32x4 v; } t;
        t.u[0] = f2bf(a.x); t.u[1] = f2bf(a.y); t.u[2] = f2bf(a.z); t.u[3] = f2bf(a.w);
        t.u[4] = f2bf(b.x); t.u[5] = f2bf(b.y); t.u[6] = f2bf(b.z); t.u[7] = f2bf(b.w);
        *(i32x4*)((char*)As + row * 128 + ((slot ^ (row & 7)) * 16)) = t.v;
    }
}
__device__ __forceinline__ void stageA_bf16(const us* A, us* As, int m0, int k0, int K, int tid) {
    #pragma unroll
    for (int i = 0; i < 2; ++i) {
        int s = tid + i * 256;
        int row = s >> 3, slot = s & 7;
        i32x4 v = *(const i32x4*)&A[(size_t)(m0 + row) * K + k0 + slot * 8];
        *(i32x4*)((char*)As + row * 128 + ((slot ^ (row & 7)) * 16)) = v;
    }
}
__device__ __forceinline__ void gemm_core(const us* As, const us* Bs, int lane, int wave,
                                          f32x4 acc[2][2]) {
    const int wr = (wave >> 1) * 32, wc = (wave & 1) * 32;
    short8 af[2][2], bf_[2][2];
    #pragma unroll
    for (int rt = 0; rt < 2; ++rt) {
        int row = wr + rt * 16 + (lane & 15);
        #pragma unroll
        for (int ks = 0; ks < 2; ++ks) {
            int slot = ks * 4 + (lane >> 4);
            af[rt][ks] = *(const short8*)((const char*)As + row * 128 + ((slot ^ (row & 7)) * 16));
        }
    }
    #pragma unroll
    for (int ct = 0; ct < 2; ++ct) {
        int row = wc + ct * 16 + (lane & 15);
        #pragma unroll
        for (int ks = 0; ks < 2; ++ks) {
            int slot = ks * 4 + (lane >> 4);
            bf_[ct][ks] = *(const short8*)((const char*)Bs + row * 128 + ((slot ^ (row & 7)) * 16));
        }
    }
    #pragma unroll
    for (int ks = 0; ks < 2; ++ks)
        #pragma unroll
        for (int rt = 0; rt < 2; ++rt)
            #pragma unroll
            for (int ct = 0; ct < 2; ++ct)
                acc[rt][ct] = __builtin_amdgcn_mfma_f32_16x16x32_bf16(
                    af[rt][ks], bf_[ct][ks], acc[rt][ct], 0, 0, 0);
}

// ---------------------------------------------------------------------------
// Fused Q & KV GEMM.  z=0: Qb = (x_q @ w_q)*0.125.  z=1: Kb / Vt from x @ w_kv.
// ---------------------------------------------------------------------------
__global__ __launch_bounds__(256) void gemm_qkv(
    const float* __restrict__ x_q, const float* __restrict__ x,
    const us* __restrict__ Wq_t, const us* __restrict__ Wkv_t,
    us* __restrict__ Qb, us* __restrict__ Kb, us* __restrict__ Vt)
{
    const int z = blockIdx.z;
    if (!z && blockIdx.x >= 8) return;
    const float* A = z ? x : x_q;
    const us* Bt   = z ? Wkv_t : Wq_t;
    const int m0 = blockIdx.y * 64, n0 = blockIdx.x * 64;

    __shared__ us smem[8192];          // As = [0,4096), Bs = [4096,8192)
    us* As = smem; us* Bs = smem + 4096;
    const int tid = threadIdx.x, lane = tid & 63, wave = tid >> 6;

    f32x4 acc[2][2] = {};
    for (int k0 = 0; k0 < 512; k0 += 64) {
        stageA_f32(A, As, m0, k0, 512, tid);
        stageA_bf16(Bt, Bs, n0, k0, 512, tid);
        __syncthreads();
        gemm_core(As, Bs, lane, wave, acc);
        __syncthreads();
    }

    const int wr = (wave >> 1) * 32, wc = (wave & 1) * 32;
    if (!z) {
        #pragma unroll
        for (int rt = 0; rt < 2; ++rt)
          #pragma unroll
          for (int ct = 0; ct < 2; ++ct)
            #pragma unroll
            for (int r = 0; r < 4; ++r) {
                int row = m0 + wr + rt * 16 + (lane >> 4) * 4 + r;
                int col = n0 + wc + ct * 16 + (lane & 15);
                Qb[(size_t)row * 512 + col] = f2bf(acc[rt][ct][r] * 0.125f);
            }
    } else if (n0 < 512) {
        #pragma unroll
        for (int rt = 0; rt < 2; ++rt)
          #pragma unroll
          for (int ct = 0; ct < 2; ++ct)
            #pragma unroll
            for (int r = 0; r < 4; ++r) {
                int row = m0 + wr + rt * 16 + (lane >> 4) * 4 + r;
                int col = n0 + wc + ct * 16 + (lane & 15);
                Kb[(size_t)row * 512 + col] = f2bf(acc[rt][ct][r]);
            }
    } else {
        // V part: transpose through LDS into Vt[(b*H+h)*64 + d][nk]
        us* T = smem;                   // 64 x 72 = 9216 B <= 16 KB
        #pragma unroll
        for (int rt = 0; rt < 2; ++rt)
          #pragma unroll
          for (int ct = 0; ct < 2; ++ct)
            #pragma unroll
            for (int r = 0; r < 4; ++r) {
                int rl = wr + rt * 16 + (lane >> 4) * 4 + r;
                int cl = wc + ct * 16 + (lane & 15);
                T[rl * 72 + cl] = f2bf(acc[rt][ct][r]);
            }
        __syncthreads();
        const int h = (n0 - 512) >> 6, bb = m0 >> 10, nk0 = m0 & 1023;
        #pragma unroll
        for (int i = 0; i < 2; ++i) {
            int s = tid + i * 256;
            int d = s >> 3, r8 = (s & 7) * 8;
            union { us u[8]; i32x4 v; } tmp;
            #pragma unroll
            for (int j = 0; j < 8; ++j) tmp.u[j] = T[(r8 + j) * 72 + d];
            *(i32x4*)&Vt[(size_t)((bb * H_ + h) * 64 + d) * NK_ + nk0 + r8] = tmp.v;
        }
    }
}

// ---------------------------------------------------------------------------
// out = Ob @ w_proj + bias   (A bf16, Bt bf16, C fp32)
// ---------------------------------------------------------------------------
__global__ __launch_bounds__(256) void gemm_out(
    const us* __restrict__ Ob, const us* __restrict__ Wp_t,
    const float* __restrict__ bias, float* __restrict__ C)
{
    const int m0 = blockIdx.y * 64, n0 = blockIdx.x * 64;
    __shared__ us smem[8192];
    us* As = smem; us* Bs = smem + 4096;
    const int tid = threadIdx.x, lane = tid & 63, wave = tid >> 6;

    f32x4 acc[2][2] = {};
    for (int k0 = 0; k0 < 512; k0 += 64) {
        stageA_bf16(Ob, As, m0, k0, 512, tid);
        stageA_bf16(Wp_t, Bs, n0, k0, 512, tid);
        __syncthreads();
        gemm_core(As, Bs, lane, wave, acc);
        __syncthreads();
    }
    const int wr = (wave >> 1) * 32, wc = (wave & 1) * 32;
    #pragma unroll
    for (int rt = 0; rt < 2; ++rt)
      #pragma unroll
      for (int ct = 0; ct < 2; ++ct)
        #pragma unroll
        for (int r = 0; r < 4; ++r) {
            int row = m0 + wr + rt * 16 + (lane >> 4) * 4 + r;
            int col = n0 + wc + ct * 16 + (lane & 15);
            C[(size_t)row * 512 + col] = acc[rt][ct][r] + bias[col];
        }
}

// ---------------------------------------------------------------------------
// Attention: block = (b,h,16 q-rows), 4 waves, wave w owns keys [256w,256w+256).
// Swapped QK^T (mfma(K,Q)) -> each lane owns ONE q-row (lane&15), 64 keys in
// 64 VGPRs. Softmax: in-reg max/sum + shfl_xor(16,32) + tiny LDS cross-wave.
// attn written straight from regs (f32x4); P packed bf16 into 32KB swizzled
// LDS for the PV MFMAs.
// ---------------------------------------------------------------------------
__global__ __launch_bounds__(256, 3) void attn2(
    const us* __restrict__ Qb, const us* __restrict__ Kb, const us* __restrict__ Vt,
    float* __restrict__ attnOut, us* __restrict__ Ob)
{
    const int tid = threadIdx.x, lane = tid & 63, w = tid >> 6;
    const int b = blockIdx.z, h = blockIdx.y, q0 = blockIdx.x * 16;
    const int q = lane & 15, q4 = lane >> 4;

    __shared__ us P[16 * 1024];          // 32 KB
    __shared__ float redM[4][16], redS[4][16];

    const us* qp = &Qb[(size_t)(b * NQ_ + q0 + q) * 512 + h * 64 + q4 * 8];
    short8 bq0 = *(const short8*)qp;
    short8 bq1 = *(const short8*)(qp + 32);

    f32x4 sv[16];
    #pragma unroll
    for (int ct = 0; ct < 16; ++ct) {
        const int key = w * 256 + ct * 16 + q;
        const us* kp = &Kb[(size_t)(b * NK_ + key) * 512 + h * 64 + q4 * 8];
        short8 ka = *(const short8*)kp;
        short8 kb2 = *(const short8*)(kp + 32);
        f32x4 acc = {};
        acc = __builtin_amdgcn_mfma_f32_16x16x32_bf16(ka, bq0, acc, 0, 0, 0);
        acc = __builtin_amdgcn_mfma_f32_16x16x32_bf16(kb2, bq1, acc, 0, 0, 0);
        sv[ct] = acc;                    // S[key = 256w+16ct+4*q4+r][q], prescaled
    }

    // row max
    float m = sv[0][0];
    #pragma unroll
    for (int ct = 0; ct < 16; ++ct)
        #pragma unroll
        for (int r = 0; r < 4; ++r) m = fmaxf(m, sv[ct][r]);
    m = fmaxf(m, __shfl_xor(m, 16));
    m = fmaxf(m, __shfl_xor(m, 32));
    if (lane < 16) redM[w][lane] = m;
    __syncthreads();
    const float mg = fmaxf(fmaxf(redM[0][q], redM[1][q]), fmaxf(redM[2][q], redM[3][q]));

    // exp + row sum
    float s = 0.f;
    #pragma unroll
    for (int ct = 0; ct < 16; ++ct)
        #pragma unroll
        for (int r = 0; r < 4; ++r) {
            float e = __expf(sv[ct][r] - mg);
            sv[ct][r] = e;
            s += e;
        }
    s += __shfl_xor(s, 16);
    s += __shfl_xor(s, 32);
    if (lane < 16) redS[w][lane] = s;
    __syncthreads();
    const float inv = 1.0f / (redS[0][q] + redS[1][q] + redS[2][q] + redS[3][q]);

    // write attn (fp32, 16B/lane) + pack P bf16 into swizzled LDS
    const size_t aBase = ((size_t)((b * H_ + h) * NQ_) + q0 + q) * NK_;
    const unsigned sw = (unsigned)(q & 7) << 4;
    #pragma unroll
    for (int ct = 0; ct < 16; ++ct) {
        const int key0 = w * 256 + ct * 16 + q4 * 4;
        f32x4 p4;
        #pragma unroll
        for (int r = 0; r < 4; ++r) p4[r] = sv[ct][r] * inv;
        *(f32x4*)&attnOut[aBase + key0] = p4;
        ull pk = (ull)f2bf(p4[0]) | ((ull)f2bf(p4[1]) << 16)
               | ((ull)f2bf(p4[2]) << 32) | ((ull)f2bf(p4[3]) << 48);
        unsigned byte = (unsigned)q * 2048u + (((unsigned)(key0 * 2)) ^ sw);
        *(ull*)((char*)P + byte) = pk;
    }
    __syncthreads();

    // PV: O[16,64] = P[16,1024] x V ; wave owns d-cols [16w,16w+16)
    f32x4 acc0 = {}, acc1 = {};
    const us* vbase = &Vt[(size_t)((b * H_ + h) * 64 + w * 16 + q) * NK_ + q4 * 8];
    #pragma unroll 4
    for (int kb = 0; kb < 1024; kb += 64) {
        unsigned o0 = ((unsigned)((kb + q4 * 8) * 2)) ^ sw;
        unsigned o1 = ((unsigned)((kb + 32 + q4 * 8) * 2)) ^ sw;
        short8 pa0 = *(const short8*)((const char*)P + (unsigned)q * 2048u + o0);
        short8 pa1 = *(const short8*)((const char*)P + (unsigned)q * 2048u + o1);
        short8 vb0 = *(const short8*)(vbase + kb);
        short8 vb1 = *(const short8*)(vbase + kb + 32);
        acc0 = __builtin_amdgcn_mfma_f32_16x16x32_bf16(pa0, vb0, acc0, 0, 0, 0);
        acc1 = __builtin_amdgcn_mfma_f32_16x16x32_bf16(pa1, vb1, acc1, 0, 0, 0);
    }
    #pragma unroll
    for (int r = 0; r < 4; ++r) {
        float o = acc0[r] + acc1[r];
        Ob[(size_t)(b * NQ_ + q0 + q4 * 4 + r) * 512 + h * 64 + w * 16 + q] = f2bf(o);
    }
}

// ---------------------------------------------------------------------------
extern "C" void kernel_launch(void* const* d_in, const int* in_sizes, int n_in,
                              void* d_out, int out_size, void* d_ws, size_t ws_size,
                              hipStream_t stream)
{
    (void)in_sizes; (void)n_in; (void)out_size; (void)ws_size;
    const float* x    = (const float*)d_in[0];
    const float* x_q  = (const float*)d_in[1];
    const float* w_q  = (const float*)d_in[2];
    const float* w_kv = (const float*)d_in[3];
    const float* w_p  = (const float*)d_in[4];
    const float* b_p  = (const float*)d_in[5];

    float* out   = (float*)d_out;
    float* attnO = out + (size_t)B_ * NQ_ * DM_;

    us* Wq_t  = (us*)d_ws;                  // 256K elems
    us* Wkv_t = Wq_t  + 262144;             // 512K
    us* Wp_t  = Wkv_t + 524288;             // 256K
    us* Qb    = Wp_t  + 262144;             // 2M
    us* Kb    = Qb    + 2097152;            // 2M
    us* Vt    = Kb    + 2097152;            // 2M
    us* Ob    = Vt    + 2097152;            // 2M   (total ~18.5 MB)

    wtrans<<<256, 256, 0, stream>>>(w_q, w_kv, w_p, Wq_t, Wkv_t, Wp_t);
    gemm_qkv<<<dim3(16, 64, 2), 256, 0, stream>>>(x_q, x, Wq_t, Wkv_t, Qb, Kb, Vt);
    attn2<<<dim3(NQ_ / 16, H_, B_), 256, 0, stream>>>(Qb, Kb, Vt, attnO, Ob);
    gemm_out<<<dim3(8, 64), 256, 0, stream>>>(Ob, Wp_t, b_p, out);
}

// Round 3
// 117.401 us; speedup vs baseline: 1.5445x; 1.0566x over previous
//
#include <hip/hip_runtime.h>

#define B_   4
#define NQ_  1024
#define NK_  1024
#define H_   8
#define DM_  512

typedef unsigned short us;
typedef unsigned long long ull;
typedef __attribute__((ext_vector_type(8))) short  short8;
typedef __attribute__((ext_vector_type(4))) float  f32x4;
typedef __attribute__((ext_vector_type(4))) int    i32x4;

static __device__ __forceinline__ us f2bf(float f) {
    unsigned int u = __builtin_bit_cast(unsigned int, f);
    u += 0x7FFF + ((u >> 16) & 1);
    return (us)(u >> 16);
}

// ---------------------------------------------------------------------------
// Weight convert+transpose: W_f32[K][N] -> Wt_bf16[N][K].  256 blocks.
// ---------------------------------------------------------------------------
__global__ __launch_bounds__(256) void wtrans(
    const float* __restrict__ wq, const float* __restrict__ wkv,
    const float* __restrict__ wp,
    us* __restrict__ Wq_t, us* __restrict__ Wkv_t, us* __restrict__ Wp_t)
{
    const int bx = blockIdx.x;
    const float* src; us* dst; int k0, n0, N; const int K = 512;
    if (bx < 64)       { src = wq;  dst = Wq_t;  N = 512;  int t = bx;       k0 = (t >> 3) * 64; n0 = (t & 7) * 64; }
    else if (bx < 192) { src = wkv; dst = Wkv_t; N = 1024; int t = bx - 64;  k0 = (t >> 4) * 64; n0 = (t & 15) * 64; }
    else               { src = wp;  dst = Wp_t;  N = 512;  int t = bx - 192; k0 = (t >> 3) * 64; n0 = (t & 7) * 64; }

    __shared__ us T[64][72];
    const int tid = threadIdx.x;
    #pragma unroll
    for (int i = 0; i < 4; ++i) {
        int s = tid + i * 256;
        int r = s >> 4, c4 = (s & 15) * 4;
        float4 v = *(const float4*)&src[(size_t)(k0 + r) * N + n0 + c4];
        T[r][c4 + 0] = f2bf(v.x); T[r][c4 + 1] = f2bf(v.y);
        T[r][c4 + 2] = f2bf(v.z); T[r][c4 + 3] = f2bf(v.w);
    }
    __syncthreads();
    #pragma unroll
    for (int i = 0; i < 2; ++i) {
        int s = tid + i * 256;
        int n = s >> 3, k8 = (s & 7) * 8;
        union { us u[8]; i32x4 v; } tmp;
        #pragma unroll
        for (int j = 0; j < 8; ++j) tmp.u[j] = T[k8 + j][n];
        *(i32x4*)&dst[(size_t)(n0 + n) * K + k0 + k8] = tmp.v;
    }
}

// ---------------------------------------------------------------------------
// Shared GEMM pieces: 64x64 tile, BK=64, linear LDS [64][64] with XOR slot
// swizzle so ds_read_b128 fragments are conflict-free.
// ---------------------------------------------------------------------------
__device__ __forceinline__ void stageA_f32(const float* A, us* As, int m0, int k0, int K, int tid) {
    #pragma unroll
    for (int i = 0; i < 2; ++i) {
        int s = tid + i * 256;
        int row = s >> 3, slot = s & 7;
        const float* p = &A[(size_t)(m0 + row) * K + k0 + slot * 8];
        float4 a = *(const float4*)p, b = *(const float4*)(p + 4);
        union { us u[8]; i32x4 v; } t;
        t.u[0] = f2bf(a.x); t.u[1] = f2bf(a.y); t.u[2] = f2bf(a.z); t.u[3] = f2bf(a.w);
        t.u[4] = f2bf(b.x); t.u[5] = f2bf(b.y); t.u[6] = f2bf(b.z); t.u[7] = f2bf(b.w);
        *(i32x4*)((char*)As + row * 128 + ((slot ^ (row & 7)) * 16)) = t.v;
    }
}
__device__ __forceinline__ void stageA_bf16(const us* A, us* As, int m0, int k0, int K, int tid) {
    #pragma unroll
    for (int i = 0; i < 2; ++i) {
        int s = tid + i * 256;
        int row = s >> 3, slot = s & 7;
        i32x4 v = *(const i32x4*)&A[(size_t)(m0 + row) * K + k0 + slot * 8];
        *(i32x4*)((char*)As + row * 128 + ((slot ^ (row & 7)) * 16)) = v;
    }
}
__device__ __forceinline__ void gemm_core(const us* As, const us* Bs, int lane, int wave,
                                          f32x4 acc[2][2]) {
    const int wr = (wave >> 1) * 32, wc = (wave & 1) * 32;
    short8 af[2][2], bf_[2][2];
    #pragma unroll
    for (int rt = 0; rt < 2; ++rt) {
        int row = wr + rt * 16 + (lane & 15);
        #pragma unroll
        for (int ks = 0; ks < 2; ++ks) {
            int slot = ks * 4 + (lane >> 4);
            af[rt][ks] = *(const short8*)((const char*)As + row * 128 + ((slot ^ (row & 7)) * 16));
        }
    }
    #pragma unroll
    for (int ct = 0; ct < 2; ++ct) {
        int row = wc + ct * 16 + (lane & 15);
        #pragma unroll
        for (int ks = 0; ks < 2; ++ks) {
            int slot = ks * 4 + (lane >> 4);
            bf_[ct][ks] = *(const short8*)((const char*)Bs + row * 128 + ((slot ^ (row & 7)) * 16));
        }
    }
    #pragma unroll
    for (int ks = 0; ks < 2; ++ks)
        #pragma unroll
        for (int rt = 0; rt < 2; ++rt)
            #pragma unroll
            for (int ct = 0; ct < 2; ++ct)
                acc[rt][ct] = __builtin_amdgcn_mfma_f32_16x16x32_bf16(
                    af[rt][ks], bf_[ct][ks], acc[rt][ct], 0, 0, 0);
}

// ---------------------------------------------------------------------------
// Fused Q & KV GEMM.  z=0: Qh = (x_q@w_q)*0.125 head-major.  z=1: Kh / Vt.
//   Qh/Kh: [b*H+h][tok][64],  Vt: [(b*H+h)*64 + d][nk]
// ---------------------------------------------------------------------------
__global__ __launch_bounds__(256) void gemm_qkv(
    const float* __restrict__ x_q, const float* __restrict__ x,
    const us* __restrict__ Wq_t, const us* __restrict__ Wkv_t,
    us* __restrict__ Qh, us* __restrict__ Kh, us* __restrict__ Vt)
{
    const int z = blockIdx.z;
    if (!z && blockIdx.x >= 8) return;
    const float* A = z ? x : x_q;
    const us* Bt   = z ? Wkv_t : Wq_t;
    const int m0 = blockIdx.y * 64, n0 = blockIdx.x * 64;

    __shared__ us smem[8192];
    us* As = smem; us* Bs = smem + 4096;
    const int tid = threadIdx.x, lane = tid & 63, wave = tid >> 6;

    f32x4 acc[2][2] = {};
    for (int k0 = 0; k0 < 512; k0 += 64) {
        stageA_f32(A, As, m0, k0, 512, tid);
        stageA_bf16(Bt, Bs, n0, k0, 512, tid);
        __syncthreads();
        gemm_core(As, Bs, lane, wave, acc);
        __syncthreads();
    }

    const int wr = (wave >> 1) * 32, wc = (wave & 1) * 32;
    if (!z || n0 < 512) {
        // head-major store: [b*H+h][tok][64]
        us* dst = z ? Kh : Qh;
        const float scale = z ? 1.0f : 0.125f;
        const int bb = m0 >> 10, hh = n0 >> 6;
        #pragma unroll
        for (int rt = 0; rt < 2; ++rt)
          #pragma unroll
          for (int ct = 0; ct < 2; ++ct)
            #pragma unroll
            for (int r = 0; r < 4; ++r) {
                int row = m0 + wr + rt * 16 + (lane >> 4) * 4 + r;
                int col = wc + ct * 16 + (lane & 15);       // d within head
                dst[(size_t)(bb * H_ + hh) * (NQ_ * 64) + (size_t)(row & 1023) * 64 + col]
                    = f2bf(acc[rt][ct][r] * scale);
            }
    } else {
        // V part: transpose through LDS into Vt[(b*H+h)*64 + d][nk]
        us* T = smem;
        #pragma unroll
        for (int rt = 0; rt < 2; ++rt)
          #pragma unroll
          for (int ct = 0; ct < 2; ++ct)
            #pragma unroll
            for (int r = 0; r < 4; ++r) {
                int rl = wr + rt * 16 + (lane >> 4) * 4 + r;
                int cl = wc + ct * 16 + (lane & 15);
                T[rl * 72 + cl] = f2bf(acc[rt][ct][r]);
            }
        __syncthreads();
        const int h = (n0 - 512) >> 6, bb = m0 >> 10, nk0 = m0 & 1023;
        #pragma unroll
        for (int i = 0; i < 2; ++i) {
            int s = tid + i * 256;
            int d = s >> 3, r8 = (s & 7) * 8;
            union { us u[8]; i32x4 v; } tmp;
            #pragma unroll
            for (int j = 0; j < 8; ++j) tmp.u[j] = T[(r8 + j) * 72 + d];
            *(i32x4*)&Vt[(size_t)((bb * H_ + h) * 64 + d) * NK_ + nk0 + r8] = tmp.v;
        }
    }
}

// ---------------------------------------------------------------------------
// out = Ob @ w_proj + bias
// ---------------------------------------------------------------------------
__global__ __launch_bounds__(256) void gemm_out(
    const us* __restrict__ Ob, const us* __restrict__ Wp_t,
    const float* __restrict__ bias, float* __restrict__ C)
{
    const int m0 = blockIdx.y * 64, n0 = blockIdx.x * 64;
    __shared__ us smem[8192];
    us* As = smem; us* Bs = smem + 4096;
    const int tid = threadIdx.x, lane = tid & 63, wave = tid >> 6;

    f32x4 acc[2][2] = {};
    for (int k0 = 0; k0 < 512; k0 += 64) {
        stageA_bf16(Ob, As, m0, k0, 512, tid);
        stageA_bf16(Wp_t, Bs, n0, k0, 512, tid);
        __syncthreads();
        gemm_core(As, Bs, lane, wave, acc);
        __syncthreads();
    }
    const int wr = (wave >> 1) * 32, wc = (wave & 1) * 32;
    #pragma unroll
    for (int rt = 0; rt < 2; ++rt)
      #pragma unroll
      for (int ct = 0; ct < 2; ++ct)
        #pragma unroll
        for (int r = 0; r < 4; ++r) {
            int row = m0 + wr + rt * 16 + (lane >> 4) * 4 + r;
            int col = n0 + wc + ct * 16 + (lane & 15);
            C[(size_t)row * 512 + col] = acc[rt][ct][r] + bias[col];
        }
}

// ---------------------------------------------------------------------------
// Attention v3: block = (b,h,16 q-rows), 4 waves.
//  - Q/K head-major: per-instr loads land in one 2KB span.
//  - Swapped QK^T: lane owns one q-row; softmax in registers.
//  - P (normalized bf16) -> swizzled LDS.
//  - attn fp32 store COALESCED: re-read P row-wise, each store instr = 1KB.
//  - PV from LDS P + head-major Vt.
// ---------------------------------------------------------------------------
__global__ __launch_bounds__(256, 3) void attn3(
    const us* __restrict__ Qhp, const us* __restrict__ Khp, const us* __restrict__ Vt,
    float* __restrict__ attnOut, us* __restrict__ Ob)
{
    const int tid = threadIdx.x, lane = tid & 63, w = tid >> 6;
    const int b = blockIdx.z, h = blockIdx.y, q0 = blockIdx.x * 16;
    const int q = lane & 15, q4 = lane >> 4;
    const int bh = b * H_ + h;

    __shared__ us P[16 * 1024];          // 32 KB
    __shared__ float redM[4][16], redS[4][16];

    const us* qp = &Qhp[(size_t)bh * (NQ_ * 64) + (size_t)(q0 + q) * 64 + q4 * 8];
    short8 bq0 = *(const short8*)qp;
    short8 bq1 = *(const short8*)(qp + 32);

    const us* kbase = &Khp[(size_t)bh * (NK_ * 64) + (size_t)q * 64 + q4 * 8];

    f32x4 sv[16];
    #pragma unroll
    for (int ct = 0; ct < 16; ++ct) {
        const us* kp = kbase + (size_t)(w * 256 + ct * 16) * 64;
        short8 ka  = *(const short8*)kp;
        short8 kb2 = *(const short8*)(kp + 32);
        f32x4 acc = {};
        acc = __builtin_amdgcn_mfma_f32_16x16x32_bf16(ka, bq0, acc, 0, 0, 0);
        acc = __builtin_amdgcn_mfma_f32_16x16x32_bf16(kb2, bq1, acc, 0, 0, 0);
        sv[ct] = acc;                    // S[key=256w+16ct+4*q4+r][q]
    }

    // row max
    float m = sv[0][0];
    #pragma unroll
    for (int ct = 0; ct < 16; ++ct)
        #pragma unroll
        for (int r = 0; r < 4; ++r) m = fmaxf(m, sv[ct][r]);
    m = fmaxf(m, __shfl_xor(m, 16));
    m = fmaxf(m, __shfl_xor(m, 32));
    if (lane < 16) redM[w][lane] = m;
    __syncthreads();
    const float mg = fmaxf(fmaxf(redM[0][q], redM[1][q]), fmaxf(redM[2][q], redM[3][q]));

    // exp + row sum
    float s = 0.f;
    #pragma unroll
    for (int ct = 0; ct < 16; ++ct)
        #pragma unroll
        for (int r = 0; r < 4; ++r) {
            float e = __expf(sv[ct][r] - mg);
            sv[ct][r] = e;
            s += e;
        }
    s += __shfl_xor(s, 16);
    s += __shfl_xor(s, 32);
    if (lane < 16) redS[w][lane] = s;
    __syncthreads();
    const float inv = 1.0f / (redS[0][q] + redS[1][q] + redS[2][q] + redS[3][q]);

    // normalize + pack P bf16 into swizzled LDS
    const unsigned sw = (unsigned)(q & 7) << 4;
    #pragma unroll
    for (int ct = 0; ct < 16; ++ct) {
        const int key0 = w * 256 + ct * 16 + q4 * 4;
        ull pk = (ull)f2bf(sv[ct][0] * inv)
               | ((ull)f2bf(sv[ct][1] * inv) << 16)
               | ((ull)f2bf(sv[ct][2] * inv) << 32)
               | ((ull)f2bf(sv[ct][3] * inv) << 48);
        unsigned byte = (unsigned)q * 2048u + (((unsigned)(key0 * 2)) ^ sw);
        *(ull*)((char*)P + byte) = pk;
    }
    __syncthreads();

    // ---- coalesced attn store: wave w stores rows 4w..4w+3, 1KB per instr ----
    {
        const size_t aRow = ((size_t)bh * NQ_ + q0) * NK_;
        #pragma unroll
        for (int i = 0; i < 4; ++i) {
            const int r = w * 4 + i;
            const unsigned swr = (unsigned)(r & 7) << 4;
            #pragma unroll
            for (int j = 0; j < 4; ++j) {
                unsigned byte = (unsigned)r * 2048u
                              + (((unsigned)(j * 512 + lane * 8)) ^ swr);
                ull pk = *(const ull*)((const char*)P + byte);
                f32x4 o;
                o[0] = __builtin_bit_cast(float, (unsigned)((pk & 0xFFFFull) << 16));
                o[1] = __builtin_bit_cast(float, (unsigned)(((pk >> 16) & 0xFFFFull) << 16));
                o[2] = __builtin_bit_cast(float, (unsigned)(((pk >> 32) & 0xFFFFull) << 16));
                o[3] = __builtin_bit_cast(float, (unsigned)((pk >> 48) << 16));
                *(f32x4*)&attnOut[aRow + (size_t)r * NK_ + j * 256 + lane * 4] = o;
            }
        }
    }

    // ---- PV: O[16,64] = P x V ; wave owns d-cols [16w,16w+16) ----
    f32x4 acc0 = {}, acc1 = {};
    const us* vbase = &Vt[(size_t)(bh * 64 + w * 16 + q) * NK_ + q4 * 8];
    #pragma unroll 4
    for (int kb = 0; kb < 1024; kb += 64) {
        unsigned o0 = ((unsigned)((kb + q4 * 8) * 2)) ^ sw;
        unsigned o1 = ((unsigned)((kb + 32 + q4 * 8) * 2)) ^ sw;
        short8 pa0 = *(const short8*)((const char*)P + (unsigned)q * 2048u + o0);
        short8 pa1 = *(const short8*)((const char*)P + (unsigned)q * 2048u + o1);
        short8 vb0 = *(const short8*)(vbase + kb);
        short8 vb1 = *(const short8*)(vbase + kb + 32);
        acc0 = __builtin_amdgcn_mfma_f32_16x16x32_bf16(pa0, vb0, acc0, 0, 0, 0);
        acc1 = __builtin_amdgcn_mfma_f32_16x16x32_bf16(pa1, vb1, acc1, 0, 0, 0);
    }
    #pragma unroll
    for (int r = 0; r < 4; ++r) {
        float o = acc0[r] + acc1[r];
        Ob[(size_t)(b * NQ_ + q0 + q4 * 4 + r) * 512 + h * 64 + w * 16 + q] = f2bf(o);
    }
}

// ---------------------------------------------------------------------------
extern "C" void kernel_launch(void* const* d_in, const int* in_sizes, int n_in,
                              void* d_out, int out_size, void* d_ws, size_t ws_size,
                              hipStream_t stream)
{
    (void)in_sizes; (void)n_in; (void)out_size; (void)ws_size;
    const float* x    = (const float*)d_in[0];
    const float* x_q  = (const float*)d_in[1];
    const float* w_q  = (const float*)d_in[2];
    const float* w_kv = (const float*)d_in[3];
    const float* w_p  = (const float*)d_in[4];
    const float* b_p  = (const float*)d_in[5];

    float* out   = (float*)d_out;
    float* attnO = out + (size_t)B_ * NQ_ * DM_;

    us* Wq_t  = (us*)d_ws;
    us* Wkv_t = Wq_t  + 262144;
    us* Wp_t  = Wkv_t + 524288;
    us* Qh    = Wp_t  + 262144;
    us* Kh    = Qh    + 2097152;
    us* Vt    = Kh    + 2097152;
    us* Ob    = Vt    + 2097152;

    wtrans<<<256, 256, 0, stream>>>(w_q, w_kv, w_p, Wq_t, Wkv_t, Wp_t);
    gemm_qkv<<<dim3(16, 64, 2), 256, 0, stream>>>(x_q, x, Wq_t, Wkv_t, Qh, Kh, Vt);
    attn3<<<dim3(NQ_ / 16, H_, B_), 256, 0, stream>>>(Qh, Kh, Vt, attnO, Ob);
    gemm_out<<<dim3(8, 64), 256, 0, stream>>>(Ob, Wp_t, b_p, out);
}

// Round 4
// 110.616 us; speedup vs baseline: 1.6392x; 1.0613x over previous
//
#include <hip/hip_runtime.h>

#define B_   4
#define NQ_  1024
#define NK_  1024
#define H_   8
#define DM_  512

typedef unsigned short us;
typedef unsigned long long ull;
typedef __attribute__((ext_vector_type(8))) short  short8;
typedef __attribute__((ext_vector_type(4))) float  f32x4;
typedef __attribute__((ext_vector_type(4))) int    i32x4;
typedef __attribute__((address_space(3))) unsigned int       lds_u32;
typedef const __attribute__((address_space(1))) unsigned int gl_u32;

static __device__ __forceinline__ us f2bf(float f) {
    unsigned int u = __builtin_bit_cast(unsigned int, f);
    u += 0x7FFF + ((u >> 16) & 1);
    return (us)(u >> 16);
}

// ---------------------------------------------------------------------------
// prep: x,x_q f32 -> bf16 [4096][512]; weights f32[K][N] -> bf16 [N][K].
// grid: 1024 (x) + 1024 (x_q) + 256 (weights) = 2304 blocks.
// ---------------------------------------------------------------------------
__global__ __launch_bounds__(256) void prep(
    const float* __restrict__ x, const float* __restrict__ x_q,
    const float* __restrict__ wq, const float* __restrict__ wkv,
    const float* __restrict__ wp,
    us* __restrict__ xb, us* __restrict__ xqb,
    us* __restrict__ Wq_t, us* __restrict__ Wkv_t, us* __restrict__ Wp_t)
{
    const int bx = blockIdx.x, tid = threadIdx.x;
    if (bx < 2048) {
        const float* src = bx < 1024 ? x : x_q;
        us* dst = bx < 1024 ? xb : xqb;
        size_t base = ((size_t)(bx & 1023) * 256 + tid) * 8;
        float4 a = *(const float4*)&src[base];
        float4 b = *(const float4*)&src[base + 4];
        union { us u[8]; i32x4 v; } t;
        t.u[0] = f2bf(a.x); t.u[1] = f2bf(a.y); t.u[2] = f2bf(a.z); t.u[3] = f2bf(a.w);
        t.u[4] = f2bf(b.x); t.u[5] = f2bf(b.y); t.u[6] = f2bf(b.z); t.u[7] = f2bf(b.w);
        *(i32x4*)&dst[base] = t.v;
        return;
    }
    const int t = bx - 2048;
    const float* src; us* dst; int k0, n0, N; const int K = 512;
    if (t < 64)       { src = wq;  dst = Wq_t;  N = 512;  k0 = (t >> 3) * 64;        n0 = (t & 7) * 64; }
    else if (t < 192) { src = wkv; dst = Wkv_t; N = 1024; k0 = ((t - 64) >> 4) * 64; n0 = ((t - 64) & 15) * 64; }
    else              { src = wp;  dst = Wp_t;  N = 512;  k0 = ((t - 192) >> 3) * 64; n0 = ((t - 192) & 7) * 64; }

    __shared__ us T[64][72];
    #pragma unroll
    for (int i = 0; i < 4; ++i) {
        int s = tid + i * 256;
        int r = s >> 4, c4 = (s & 15) * 4;
        float4 v = *(const float4*)&src[(size_t)(k0 + r) * N + n0 + c4];
        T[r][c4 + 0] = f2bf(v.x); T[r][c4 + 1] = f2bf(v.y);
        T[r][c4 + 2] = f2bf(v.z); T[r][c4 + 3] = f2bf(v.w);
    }
    __syncthreads();
    #pragma unroll
    for (int i = 0; i < 2; ++i) {
        int s = tid + i * 256;
        int n = s >> 3, k8 = (s & 7) * 8;
        union { us u[8]; i32x4 v; } tmp;
        #pragma unroll
        for (int j = 0; j < 8; ++j) tmp.u[j] = T[k8 + j][n];
        *(i32x4*)&dst[(size_t)(n0 + n) * K + k0 + k8] = tmp.v;
    }
}

// ---------------------------------------------------------------------------
// 128x128 tile GEMM core pieces (BK=64, 4 waves, global_load_lds staging with
// pre-swizzled global source -> linear LDS; frag reads XOR-unswizzle).
// ---------------------------------------------------------------------------
__device__ __forceinline__ void stage128(const us* gA, const us* gB,
                                         us* As, us* Bs, int w, int k0)
{
    #pragma unroll
    for (int i = 0; i < 4; ++i) {
        __builtin_amdgcn_global_load_lds((gl_u32*)(gA + (size_t)i * 8 * 512 + k0),
                                         (lds_u32*)(As + (w * 32 + i * 8) * 64), 16, 0, 0);
        __builtin_amdgcn_global_load_lds((gl_u32*)(gB + (size_t)i * 8 * 512 + k0),
                                         (lds_u32*)(Bs + (w * 32 + i * 8) * 64), 16, 0, 0);
    }
}
__device__ __forceinline__ void core128(const us* As, const us* Bs, int l, int w,
                                        f32x4 acc[4][4])
{
    const int wr = (w >> 1) * 64, wc = (w & 1) * 64;
    short8 af[4][2], bf_[4][2];
    #pragma unroll
    for (int rt = 0; rt < 4; ++rt) {
        int row = wr + rt * 16 + (l & 15);
        #pragma unroll
        for (int ks = 0; ks < 2; ++ks) {
            int slot = ks * 4 + (l >> 4);
            af[rt][ks] = *(const short8*)((const char*)As + row * 128 + ((slot ^ (row & 7)) * 16));
        }
    }
    #pragma unroll
    for (int ct = 0; ct < 4; ++ct) {
        int row = wc + ct * 16 + (l & 15);
        #pragma unroll
        for (int ks = 0; ks < 2; ++ks) {
            int slot = ks * 4 + (l >> 4);
            bf_[ct][ks] = *(const short8*)((const char*)Bs + row * 128 + ((slot ^ (row & 7)) * 16));
        }
    }
    #pragma unroll
    for (int ks = 0; ks < 2; ++ks)
        #pragma unroll
        for (int rt = 0; rt < 4; ++rt)
            #pragma unroll
            for (int ct = 0; ct < 4; ++ct)
                acc[rt][ct] = __builtin_amdgcn_mfma_f32_16x16x32_bf16(
                    af[rt][ks], bf_[ct][ks], acc[rt][ct], 0, 0, 0);
}

// ---------------------------------------------------------------------------
// Q/K GEMM: z=0: Qh = (xqb @ Wq_t^T)*0.125 ; z=1: Kh = xb @ Wkv_t[0:512]^T.
// Head-major epilogue: dst[b*H+h][tok][64].
// ---------------------------------------------------------------------------
__global__ __launch_bounds__(256, 2) void qk128(
    const us* __restrict__ xqb, const us* __restrict__ xb,
    const us* __restrict__ Wq_t, const us* __restrict__ Wkv_t,
    us* __restrict__ Qh, us* __restrict__ Kh)
{
    const int z = blockIdx.z;
    const us* A  = z ? xb : xqb;
    const us* Bt = z ? Wkv_t : Wq_t;
    us* dst      = z ? Kh : Qh;
    const float scale = z ? 1.0f : 0.125f;

    __shared__ us As[128 * 64], Bs[128 * 64];
    const int tid = threadIdx.x, l = tid & 63, w = tid >> 6;
    const int m0 = blockIdx.y * 128, n0 = blockIdx.x * 128;

    const int rr0 = w * 32 + (l >> 3);
    const int ss  = (l & 7) ^ ((l >> 3) & 7);
    const us* gA = A  + (size_t)(m0 + rr0) * 512 + ss * 8;
    const us* gB = Bt + (size_t)(n0 + rr0) * 512 + ss * 8;

    f32x4 acc[4][4] = {};
    for (int k0 = 0; k0 < 512; k0 += 64) {
        stage128(gA, gB, As, Bs, w, k0);
        __syncthreads();
        core128(As, Bs, l, w, acc);
        __syncthreads();
    }

    const int wr = (w >> 1) * 64, wc = (w & 1) * 64;
    #pragma unroll
    for (int rt = 0; rt < 4; ++rt)
      #pragma unroll
      for (int ct = 0; ct < 4; ++ct)
        #pragma unroll
        for (int r = 0; r < 4; ++r) {
            int row = m0 + wr + rt * 16 + (l >> 4) * 4 + r;
            int col = n0 + wc + ct * 16 + (l & 15);
            int hh = col >> 6, d = col & 63;
            dst[((size_t)((row >> 10) * H_ + hh) << 16) + (size_t)(row & 1023) * 64 + d]
                = f2bf(acc[rt][ct][r] * scale);
        }
}

// ---------------------------------------------------------------------------
// out = Ob @ Wp_t^T + bias  (fp32 out)
// ---------------------------------------------------------------------------
__global__ __launch_bounds__(256, 2) void out128(
    const us* __restrict__ Ob, const us* __restrict__ Wp_t,
    const float* __restrict__ bias, float* __restrict__ C)
{
    __shared__ us As[128 * 64], Bs[128 * 64];
    const int tid = threadIdx.x, l = tid & 63, w = tid >> 6;
    const int m0 = blockIdx.y * 128, n0 = blockIdx.x * 128;

    const int rr0 = w * 32 + (l >> 3);
    const int ss  = (l & 7) ^ ((l >> 3) & 7);
    const us* gA = Ob   + (size_t)(m0 + rr0) * 512 + ss * 8;
    const us* gB = Wp_t + (size_t)(n0 + rr0) * 512 + ss * 8;

    f32x4 acc[4][4] = {};
    for (int k0 = 0; k0 < 512; k0 += 64) {
        stage128(gA, gB, As, Bs, w, k0);
        __syncthreads();
        core128(As, Bs, l, w, acc);
        __syncthreads();
    }

    const int wr = (w >> 1) * 64, wc = (w & 1) * 64;
    #pragma unroll
    for (int rt = 0; rt < 4; ++rt)
      #pragma unroll
      for (int ct = 0; ct < 4; ++ct)
        #pragma unroll
        for (int r = 0; r < 4; ++r) {
            int row = m0 + wr + rt * 16 + (l >> 4) * 4 + r;
            int col = n0 + wc + ct * 16 + (l & 15);
            C[(size_t)row * 512 + col] = acc[rt][ct][r] + bias[col];
        }
}

// ---------------------------------------------------------------------------
// V GEMM (64x64 tile, proven path): Vt[(b*H+h)*64+d][nk] = (xb @ Wkv_t[512:])^T
// ---------------------------------------------------------------------------
__device__ __forceinline__ void stageA_bf16(const us* A, us* As, int m0, int k0, int K, int tid) {
    #pragma unroll
    for (int i = 0; i < 2; ++i) {
        int s = tid + i * 256;
        int row = s >> 3, slot = s & 7;
        i32x4 v = *(const i32x4*)&A[(size_t)(m0 + row) * K + k0 + slot * 8];
        *(i32x4*)((char*)As + row * 128 + ((slot ^ (row & 7)) * 16)) = v;
    }
}
__device__ __forceinline__ void gemm_core(const us* As, const us* Bs, int lane, int wave,
                                          f32x4 acc[2][2]) {
    const int wr = (wave >> 1) * 32, wc = (wave & 1) * 32;
    short8 af[2][2], bf_[2][2];
    #pragma unroll
    for (int rt = 0; rt < 2; ++rt) {
        int row = wr + rt * 16 + (lane & 15);
        #pragma unroll
        for (int ks = 0; ks < 2; ++ks) {
            int slot = ks * 4 + (lane >> 4);
            af[rt][ks] = *(const short8*)((const char*)As + row * 128 + ((slot ^ (row & 7)) * 16));
        }
    }
    #pragma unroll
    for (int ct = 0; ct < 2; ++ct) {
        int row = wc + ct * 16 + (lane & 15);
        #pragma unroll
        for (int ks = 0; ks < 2; ++ks) {
            int slot = ks * 4 + (lane >> 4);
            bf_[ct][ks] = *(const short8*)((const char*)Bs + row * 128 + ((slot ^ (row & 7)) * 16));
        }
    }
    #pragma unroll
    for (int ks = 0; ks < 2; ++ks)
        #pragma unroll
        for (int rt = 0; rt < 2; ++rt)
            #pragma unroll
            for (int ct = 0; ct < 2; ++ct)
                acc[rt][ct] = __builtin_amdgcn_mfma_f32_16x16x32_bf16(
                    af[rt][ks], bf_[ct][ks], acc[rt][ct], 0, 0, 0);
}

__global__ __launch_bounds__(256) void gemm64v(
    const us* __restrict__ xb, const us* __restrict__ Wkv_t, us* __restrict__ Vt)
{
    const int m0 = blockIdx.y * 64, n0 = 512 + blockIdx.x * 64;
    __shared__ us smem[8192];
    us* As = smem; us* Bs = smem + 4096;
    const int tid = threadIdx.x, lane = tid & 63, wave = tid >> 6;

    f32x4 acc[2][2] = {};
    for (int k0 = 0; k0 < 512; k0 += 64) {
        stageA_bf16(xb, As, m0, k0, 512, tid);
        stageA_bf16(Wkv_t, Bs, n0, k0, 512, tid);
        __syncthreads();
        gemm_core(As, Bs, lane, wave, acc);
        __syncthreads();
    }
    const int wr = (wave >> 1) * 32, wc = (wave & 1) * 32;
    us* T = smem;
    #pragma unroll
    for (int rt = 0; rt < 2; ++rt)
      #pragma unroll
      for (int ct = 0; ct < 2; ++ct)
        #pragma unroll
        for (int r = 0; r < 4; ++r) {
            int rl = wr + rt * 16 + (lane >> 4) * 4 + r;
            int cl = wc + ct * 16 + (lane & 15);
            T[rl * 72 + cl] = f2bf(acc[rt][ct][r]);
        }
    __syncthreads();
    const int h = (n0 - 512) >> 6, bb = m0 >> 10, nk0 = m0 & 1023;
    #pragma unroll
    for (int i = 0; i < 2; ++i) {
        int s = tid + i * 256;
        int d = s >> 3, r8 = (s & 7) * 8;
        union { us u[8]; i32x4 v; } tmp;
        #pragma unroll
        for (int j = 0; j < 8; ++j) tmp.u[j] = T[(r8 + j) * 72 + d];
        *(i32x4*)&Vt[(size_t)((bb * H_ + h) * 64 + d) * NK_ + nk0 + r8] = tmp.v;
    }
}

// ---------------------------------------------------------------------------
// Attention v4: block = (b,h,32 q-rows), 8 waves (512 thr).
// wave w: row-group g=w>>2 (16 rows), key-quarter wk=w&3 (256 keys).
// Wave pairs (g=0,g=1) load identical K and V lines -> L1 reuse, L2 traffic /2.
// ---------------------------------------------------------------------------
__global__ __launch_bounds__(512, 4) void attn4(
    const us* __restrict__ Qhp, const us* __restrict__ Khp, const us* __restrict__ Vt,
    float* __restrict__ attnOut, us* __restrict__ Ob)
{
    const int tid = threadIdx.x, lane = tid & 63, w = tid >> 6;
    const int g = w >> 2, wk = w & 3;
    const int b = blockIdx.z, h = blockIdx.y, q0 = blockIdx.x * 32;
    const int q = lane & 15, q4 = lane >> 4;
    const int bh = b * H_ + h;

    __shared__ us P[32 * 1024];              // 64 KB
    __shared__ float redM[2][4][16], redS[2][4][16];

    const us* qp = &Qhp[((size_t)bh << 16) + (size_t)(q0 + g * 16 + q) * 64 + q4 * 8];
    short8 bq0 = *(const short8*)qp;
    short8 bq1 = *(const short8*)(qp + 32);

    const us* kbase = &Khp[((size_t)bh << 16) + (size_t)q * 64 + q4 * 8];

    f32x4 sv[16];
    #pragma unroll
    for (int ct = 0; ct < 16; ++ct) {
        const us* kp = kbase + (size_t)(wk * 256 + ct * 16) * 64;
        short8 ka  = *(const short8*)kp;
        short8 kb2 = *(const short8*)(kp + 32);
        f32x4 a = {};
        a = __builtin_amdgcn_mfma_f32_16x16x32_bf16(ka, bq0, a, 0, 0, 0);
        a = __builtin_amdgcn_mfma_f32_16x16x32_bf16(kb2, bq1, a, 0, 0, 0);
        sv[ct] = a;                          // S[key=256wk+16ct+4q4+r][row q of group g]
    }

    float m = sv[0][0];
    #pragma unroll
    for (int ct = 0; ct < 16; ++ct)
        #pragma unroll
        for (int r = 0; r < 4; ++r) m = fmaxf(m, sv[ct][r]);
    m = fmaxf(m, __shfl_xor(m, 16));
    m = fmaxf(m, __shfl_xor(m, 32));
    if (lane < 16) redM[g][wk][lane] = m;
    __syncthreads();
    const float mg = fmaxf(fmaxf(redM[g][0][q], redM[g][1][q]),
                           fmaxf(redM[g][2][q], redM[g][3][q]));

    float s = 0.f;
    #pragma unroll
    for (int ct = 0; ct < 16; ++ct)
        #pragma unroll
        for (int r = 0; r < 4; ++r) {
            float e = __expf(sv[ct][r] - mg);
            sv[ct][r] = e;
            s += e;
        }
    s += __shfl_xor(s, 16);
    s += __shfl_xor(s, 32);
    if (lane < 16) redS[g][wk][lane] = s;
    __syncthreads();
    const float inv = 1.0f / (redS[g][0][q] + redS[g][1][q] + redS[g][2][q] + redS[g][3][q]);

    // normalize + pack P bf16 into swizzled LDS (row = g*16+q, stride 2048B)
    const unsigned sw = (unsigned)(q & 7) << 4;
    #pragma unroll
    for (int ct = 0; ct < 16; ++ct) {
        const int key0 = wk * 256 + ct * 16 + q4 * 4;
        ull pk = (ull)f2bf(sv[ct][0] * inv)
               | ((ull)f2bf(sv[ct][1] * inv) << 16)
               | ((ull)f2bf(sv[ct][2] * inv) << 32)
               | ((ull)f2bf(sv[ct][3] * inv) << 48);
        unsigned byte = (unsigned)(g * 16 + q) * 2048u + (((unsigned)(key0 * 2)) ^ sw);
        *(ull*)((char*)P + byte) = pk;
    }
    __syncthreads();

    // coalesced attn store: wave w stores block-rows w*4 .. w*4+3 (1KB/instr)
    {
        const size_t aRow = ((size_t)bh * NQ_ + q0) * NK_;
        #pragma unroll
        for (int i = 0; i < 4; ++i) {
            const int r = w * 4 + i;
            const unsigned swr = (unsigned)(r & 7) << 4;
            #pragma unroll
            for (int j = 0; j < 4; ++j) {
                unsigned byte = (unsigned)r * 2048u
                              + (((unsigned)(j * 512 + lane * 8)) ^ swr);
                ull pk = *(const ull*)((const char*)P + byte);
                f32x4 o;
                o[0] = __builtin_bit_cast(float, (unsigned)((pk & 0xFFFFull) << 16));
                o[1] = __builtin_bit_cast(float, (unsigned)(((pk >> 16) & 0xFFFFull) << 16));
                o[2] = __builtin_bit_cast(float, (unsigned)(((pk >> 32) & 0xFFFFull) << 16));
                o[3] = __builtin_bit_cast(float, (unsigned)((pk >> 48) << 16));
                *(f32x4*)&attnOut[aRow + (size_t)r * NK_ + j * 256 + lane * 4] = o;
            }
        }
    }

    // PV: rows of group g x d-cols [16wk,16wk+16)
    f32x4 acc0 = {}, acc1 = {};
    const us* vbase = &Vt[(size_t)(bh * 64 + wk * 16 + q) * NK_ + q4 * 8];
    const unsigned prow = (unsigned)(g * 16 + q) * 2048u;
    #pragma unroll 4
    for (int kb = 0; kb < 1024; kb += 64) {
        unsigned o0 = ((unsigned)((kb + q4 * 8) * 2)) ^ sw;
        unsigned o1 = ((unsigned)((kb + 32 + q4 * 8) * 2)) ^ sw;
        short8 pa0 = *(const short8*)((const char*)P + prow + o0);
        short8 pa1 = *(const short8*)((const char*)P + prow + o1);
        short8 vb0 = *(const short8*)(vbase + kb);
        short8 vb1 = *(const short8*)(vbase + kb + 32);
        acc0 = __builtin_amdgcn_mfma_f32_16x16x32_bf16(pa0, vb0, acc0, 0, 0, 0);
        acc1 = __builtin_amdgcn_mfma_f32_16x16x32_bf16(pa1, vb1, acc1, 0, 0, 0);
    }
    #pragma unroll
    for (int r = 0; r < 4; ++r) {
        float o = acc0[r] + acc1[r];
        Ob[(size_t)(b * NQ_ + q0 + g * 16 + q4 * 4 + r) * 512 + h * 64 + wk * 16 + q] = f2bf(o);
    }
}

// ---------------------------------------------------------------------------
extern "C" void kernel_launch(void* const* d_in, const int* in_sizes, int n_in,
                              void* d_out, int out_size, void* d_ws, size_t ws_size,
                              hipStream_t stream)
{
    (void)in_sizes; (void)n_in; (void)out_size; (void)ws_size;
    const float* x    = (const float*)d_in[0];
    const float* x_q  = (const float*)d_in[1];
    const float* w_q  = (const float*)d_in[2];
    const float* w_kv = (const float*)d_in[3];
    const float* w_p  = (const float*)d_in[4];
    const float* b_p  = (const float*)d_in[5];

    float* out   = (float*)d_out;
    float* attnO = out + (size_t)B_ * NQ_ * DM_;

    us* xb    = (us*)d_ws;                  // 2M elems
    us* xqb   = xb    + 2097152;            // 2M
    us* Wq_t  = xqb   + 2097152;            // 256K
    us* Wkv_t = Wq_t  + 262144;             // 512K
    us* Wp_t  = Wkv_t + 524288;             // 256K
    us* Qh    = Wp_t  + 262144;             // 2M
    us* Kh    = Qh    + 2097152;            // 2M
    us* Vt    = Kh    + 2097152;            // 2M
    us* Ob    = Vt    + 2097152;            // 2M  (~26.5 MB total)

    prep<<<2304, 256, 0, stream>>>(x, x_q, w_q, w_kv, w_p, xb, xqb, Wq_t, Wkv_t, Wp_t);
    qk128<<<dim3(4, 32, 2), 256, 0, stream>>>(xqb, xb, Wq_t, Wkv_t, Qh, Kh);
    gemm64v<<<dim3(8, 64), 256, 0, stream>>>(xb, Wkv_t, Vt);
    attn4<<<dim3(NQ_ / 32, H_, B_), 512, 0, stream>>>(Qh, Kh, Vt, attnO, Ob);
    out128<<<dim3(4, 32), 256, 0, stream>>>(Ob, Wp_t, b_p, out);
}

// Round 5
// 83.435 us; speedup vs baseline: 2.1732x; 1.3258x over previous
//
#include <hip/hip_runtime.h>

#define B_   4
#define NQ_  1024
#define NK_  1024
#define H_   8
#define DM_  512

typedef unsigned short us;
typedef unsigned long long ull;
typedef __attribute__((ext_vector_type(8))) short  short8;
typedef __attribute__((ext_vector_type(4))) float  f32x4;
typedef __attribute__((ext_vector_type(4))) int    i32x4;
typedef __attribute__((address_space(3))) unsigned int       lds_u32;
typedef const __attribute__((address_space(1))) unsigned int gl_u32;

static __device__ __forceinline__ us f2bf(float f) {
    unsigned int u = __builtin_bit_cast(unsigned int, f);
    u += 0x7FFF + ((u >> 16) & 1);
    return (us)(u >> 16);
}

// ---------------------------------------------------------------------------
// wprep: weights f32[K][N] -> bf16 [N][K].  256 blocks.
// ---------------------------------------------------------------------------
__global__ __launch_bounds__(256) void wprep(
    const float* __restrict__ wq, const float* __restrict__ wkv,
    const float* __restrict__ wp,
    us* __restrict__ Wq_t, us* __restrict__ Wkv_t, us* __restrict__ Wp_t)
{
    const int t = blockIdx.x, tid = threadIdx.x;
    const float* src; us* dst; int k0, n0, N; const int K = 512;
    if (t < 64)       { src = wq;  dst = Wq_t;  N = 512;  k0 = (t >> 3) * 64;         n0 = (t & 7) * 64; }
    else if (t < 192) { src = wkv; dst = Wkv_t; N = 1024; k0 = ((t - 64) >> 4) * 64;  n0 = ((t - 64) & 15) * 64; }
    else              { src = wp;  dst = Wp_t;  N = 512;  k0 = ((t - 192) >> 3) * 64; n0 = ((t - 192) & 7) * 64; }

    __shared__ us T[64][72];
    #pragma unroll
    for (int i = 0; i < 4; ++i) {
        int s = tid + i * 256;
        int r = s >> 4, c4 = (s & 15) * 4;
        float4 v = *(const float4*)&src[(size_t)(k0 + r) * N + n0 + c4];
        T[r][c4 + 0] = f2bf(v.x); T[r][c4 + 1] = f2bf(v.y);
        T[r][c4 + 2] = f2bf(v.z); T[r][c4 + 3] = f2bf(v.w);
    }
    __syncthreads();
    #pragma unroll
    for (int i = 0; i < 2; ++i) {
        int s = tid + i * 256;
        int n = s >> 3, k8 = (s & 7) * 8;
        union { us u[8]; i32x4 v; } tmp;
        #pragma unroll
        for (int j = 0; j < 8; ++j) tmp.u[j] = T[k8 + j][n];
        *(i32x4*)&dst[(size_t)(n0 + n) * K + k0 + k8] = tmp.v;
    }
}

// ---------------------------------------------------------------------------
// 128x128 core (BK=64): reads As/Bs with XOR slot swizzle.
// ---------------------------------------------------------------------------
__device__ __forceinline__ void core128(const us* As, const us* Bs, int l, int w,
                                        f32x4 acc[4][4])
{
    const int wr = (w >> 1) * 64, wc = (w & 1) * 64;
    short8 af[4][2], bf_[4][2];
    #pragma unroll
    for (int rt = 0; rt < 4; ++rt) {
        int row = wr + rt * 16 + (l & 15);
        #pragma unroll
        for (int ks = 0; ks < 2; ++ks) {
            int slot = ks * 4 + (l >> 4);
            af[rt][ks] = *(const short8*)((const char*)As + row * 128 + ((slot ^ (row & 7)) * 16));
        }
    }
    #pragma unroll
    for (int ct = 0; ct < 4; ++ct) {
        int row = wc + ct * 16 + (l & 15);
        #pragma unroll
        for (int ks = 0; ks < 2; ++ks) {
            int slot = ks * 4 + (l >> 4);
            bf_[ct][ks] = *(const short8*)((const char*)Bs + row * 128 + ((slot ^ (row & 7)) * 16));
        }
    }
    #pragma unroll
    for (int ks = 0; ks < 2; ++ks)
        #pragma unroll
        for (int rt = 0; rt < 4; ++rt)
            #pragma unroll
            for (int ct = 0; ct < 4; ++ct)
                acc[rt][ct] = __builtin_amdgcn_mfma_f32_16x16x32_bf16(
                    af[rt][ks], bf_[ct][ks], acc[rt][ct], 0, 0, 0);
}

// ---------------------------------------------------------------------------
// Fused QKV GEMM: z=0 Qh(*0.125), z=1 Kpack, z=2 Vpack.
// A: f32 reg-staged (convert in regs, ds_write); B: bf16 global_load_lds.
// Kpack layout per bh (128KB): tile ct(16 keys): byte = ct*2048 + p*1024
//   + (q4*16+q)*16 + e*2  holds K[16ct+q][p*32+q4*8+e].
// Vpack layout per bh (128KB): byte = ((dt*16+kt)*2+p)*1024 + (q4*16+q)*16
//   + e*2 holds V[kt*64+p*32+q4*8+e][dt*16+q].
// ---------------------------------------------------------------------------
__global__ __launch_bounds__(256, 2) void qkv128(
    const float* __restrict__ x_q, const float* __restrict__ x,
    const us* __restrict__ Wq_t, const us* __restrict__ Wkv_t,
    us* __restrict__ Qh, us* __restrict__ Kpack, us* __restrict__ Vpack)
{
    const int z = blockIdx.z;
    const float* Af = z ? x : x_q;
    const us* Bt    = z ? Wkv_t : Wq_t;
    const int m0 = blockIdx.y * 128, n0 = blockIdx.x * 128;
    const int bn0 = n0 + (z == 2 ? 512 : 0);

    __shared__ us smem[16896];               // As 16KB | Bs 16KB ; T reuses all
    us* As = smem; us* Bs = smem + 8192;
    const int tid = threadIdx.x, l = tid & 63, w = tid >> 6;

    const int rr0 = w * 32 + (l >> 3);
    const int ss  = (l & 7) ^ ((l >> 3) & 7);
    const us* gB = Bt + (size_t)(bn0 + rr0) * 512 + ss * 8;
    const float* gA = Af + (size_t)(m0 + w * 32 + (l >> 4)) * 512 + (l & 15) * 4;

    f32x4 acc[4][4] = {};
    for (int k0 = 0; k0 < 512; k0 += 64) {
        #pragma unroll
        for (int i = 0; i < 4; ++i)
            __builtin_amdgcn_global_load_lds((gl_u32*)(gB + (size_t)i * 8 * 512 + k0),
                                             (lds_u32*)(Bs + (w * 32 + i * 8) * 64), 16, 0, 0);
        #pragma unroll
        for (int j = 0; j < 8; ++j) {
            float4 f = *(const float4*)(gA + (size_t)j * 4 * 512 + k0);
            int row = w * 32 + j * 4 + (l >> 4);
            ull pk = (ull)f2bf(f.x) | ((ull)f2bf(f.y) << 16)
                   | ((ull)f2bf(f.z) << 32) | ((ull)f2bf(f.w) << 48);
            int slot = (l & 15) >> 1, sub = l & 1;
            *(ull*)((char*)As + row * 128 + ((slot ^ (row & 7)) * 16) + sub * 8) = pk;
        }
        __syncthreads();
        core128(As, Bs, l, w, acc);
        __syncthreads();
    }

    const int wr = (w >> 1) * 64, wc = (w & 1) * 64;
    if (z == 0) {
        #pragma unroll
        for (int rt = 0; rt < 4; ++rt)
          #pragma unroll
          for (int ct = 0; ct < 4; ++ct)
            #pragma unroll
            for (int r = 0; r < 4; ++r) {
                int row = m0 + wr + rt * 16 + (l >> 4) * 4 + r;
                int col = n0 + wc + ct * 16 + (l & 15);
                int hh = col >> 6, d = col & 63;
                Qh[((size_t)((row >> 10) * H_ + hh) << 16) + (size_t)(row & 1023) * 64 + d]
                    = f2bf(acc[rt][ct][r] * 0.125f);
            }
    } else if (z == 1) {
        #pragma unroll
        for (int rt = 0; rt < 4; ++rt)
          #pragma unroll
          for (int ct = 0; ct < 4; ++ct)
            #pragma unroll
            for (int r = 0; r < 4; ++r) {
                int row = m0 + wr + rt * 16 + (l >> 4) * 4 + r;
                int col = n0 + wc + ct * 16 + (l & 15);
                int hh = col >> 6, d = col & 63;
                int bh = (row >> 10) * H_ + hh, tl = row & 1023;
                size_t byte = ((size_t)bh << 17) + (size_t)(tl >> 4) * 2048
                            + (size_t)(d >> 5) * 1024
                            + ((((d >> 3) & 3) * 16 + (tl & 15)) * 16) + (d & 7) * 2;
                *(us*)((char*)Kpack + byte) = f2bf(acc[rt][ct][r]);
            }
    } else {
        us* T = smem;                        // [128][132]
        #pragma unroll
        for (int rt = 0; rt < 4; ++rt)
          #pragma unroll
          for (int ct = 0; ct < 4; ++ct)
            #pragma unroll
            for (int r = 0; r < 4; ++r) {
                int rl = wr + rt * 16 + (l >> 4) * 4 + r;
                int cl = wc + ct * 16 + (l & 15);
                T[rl * 132 + cl] = f2bf(acc[rt][ct][r]);
            }
        __syncthreads();
        const int bb = m0 >> 10, tb = m0 & 1023;
        #pragma unroll
        for (int i = 0; i < 8; ++i) {
            int s = tid + i * 256;
            int col = s >> 4, r8 = (s & 15) * 8;
            union { us u[8]; i32x4 v; } tmp;
            #pragma unroll
            for (int j = 0; j < 8; ++j) tmp.u[j] = T[(r8 + j) * 132 + col];
            int gcol = n0 + col;
            int hh = gcol >> 6, d = gcol & 63;
            int bh = bb * H_ + hh;
            int tl0 = tb + r8;
            int dt = d >> 4, q = d & 15;
            int kt = tl0 >> 6, koff = tl0 & 63;
            int p = koff >> 5, q4 = (koff >> 3) & 3;
            size_t byte = ((size_t)bh << 17) + (size_t)((dt * 16 + kt) * 2 + p) * 1024
                        + (q4 * 16 + q) * 16;
            *(i32x4*)((char*)Vpack + byte) = tmp.v;
        }
    }
}

// ---------------------------------------------------------------------------
// out = Ob @ Wp_t^T + bias  (A bf16 global_load_lds, nt fp32 stores)
// ---------------------------------------------------------------------------
__global__ __launch_bounds__(256, 2) void out128(
    const us* __restrict__ Ob, const us* __restrict__ Wp_t,
    const float* __restrict__ bias, float* __restrict__ C)
{
    __shared__ us As[128 * 64], Bs[128 * 64];
    const int tid = threadIdx.x, l = tid & 63, w = tid >> 6;
    const int m0 = blockIdx.y * 128, n0 = blockIdx.x * 128;

    const int rr0 = w * 32 + (l >> 3);
    const int ss  = (l & 7) ^ ((l >> 3) & 7);
    const us* gA = Ob   + (size_t)(m0 + rr0) * 512 + ss * 8;
    const us* gB = Wp_t + (size_t)(n0 + rr0) * 512 + ss * 8;

    f32x4 acc[4][4] = {};
    for (int k0 = 0; k0 < 512; k0 += 64) {
        #pragma unroll
        for (int i = 0; i < 4; ++i) {
            __builtin_amdgcn_global_load_lds((gl_u32*)(gA + (size_t)i * 8 * 512 + k0),
                                             (lds_u32*)(As + (w * 32 + i * 8) * 64), 16, 0, 0);
            __builtin_amdgcn_global_load_lds((gl_u32*)(gB + (size_t)i * 8 * 512 + k0),
                                             (lds_u32*)(Bs + (w * 32 + i * 8) * 64), 16, 0, 0);
        }
        __syncthreads();
        core128(As, Bs, l, w, acc);
        __syncthreads();
    }

    const int wr = (w >> 1) * 64, wc = (w & 1) * 64;
    #pragma unroll
    for (int rt = 0; rt < 4; ++rt)
      #pragma unroll
      for (int ct = 0; ct < 4; ++ct)
        #pragma unroll
        for (int r = 0; r < 4; ++r) {
            int row = m0 + wr + rt * 16 + (l >> 4) * 4 + r;
            int col = n0 + wc + ct * 16 + (l & 15);
            __builtin_nontemporal_store(acc[rt][ct][r] + bias[col], &C[(size_t)row * 512 + col]);
        }
}

// ---------------------------------------------------------------------------
// Attention v5: 32 q-rows, 8 waves; XCD-grouped blocks; fragment-native
// Kpack/Vpack 1KB-coalesced loads; nt attn stores; V prefetch; setprio PV.
// ---------------------------------------------------------------------------
__global__ __launch_bounds__(512, 4) void attn5(
    const us* __restrict__ Qhp, const us* __restrict__ Kpack, const us* __restrict__ Vpack,
    float* __restrict__ attnOut, us* __restrict__ Ob)
{
    const int tid = threadIdx.x, lane = tid & 63, w = tid >> 6;
    const int rg = w >> 2, wk = w & 3;
    // XCD-group remap: all 32 q-blocks of one (b,h) on one XCD (dispatch %8)
    const int p = blockIdx.x + 32 * blockIdx.y + 256 * blockIdx.z;
    const int g = (p & 7) + 8 * ((p >> 3) & 3);
    const int b = g >> 3, h = g & 7, q0 = (p >> 5) * 32;
    const int q = lane & 15, q4 = lane >> 4;
    const int bh = b * H_ + h;

    __shared__ us P[32 * 1024];              // 64 KB
    __shared__ float redM[2][4][16], redS[2][4][16];

    const us* qp = &Qhp[((size_t)bh << 16) + (size_t)(q0 + rg * 16 + q) * 64 + q4 * 8];
    short8 bq0 = *(const short8*)qp;
    short8 bq1 = *(const short8*)(qp + 32);

    const char* kb_base = (const char*)Kpack + ((size_t)bh << 17) + (size_t)wk * 16 * 2048 + lane * 16;

    f32x4 sv[16];
    #pragma unroll
    for (int ct = 0; ct < 16; ++ct) {
        const char* ka_ = kb_base + ct * 2048;
        short8 ka  = *(const short8*)ka_;
        short8 kb2 = *(const short8*)(ka_ + 1024);
        f32x4 a = {};
        a = __builtin_amdgcn_mfma_f32_16x16x32_bf16(ka, bq0, a, 0, 0, 0);
        a = __builtin_amdgcn_mfma_f32_16x16x32_bf16(kb2, bq1, a, 0, 0, 0);
        sv[ct] = a;                          // S[key=256wk+16ct+4q4+r][row q of group rg]
    }

    float m = sv[0][0];
    #pragma unroll
    for (int ct = 0; ct < 16; ++ct)
        #pragma unroll
        for (int r = 0; r < 4; ++r) m = fmaxf(m, sv[ct][r]);
    m = fmaxf(m, __shfl_xor(m, 16));
    m = fmaxf(m, __shfl_xor(m, 32));
    if (lane < 16) redM[rg][wk][lane] = m;
    __syncthreads();
    const float mg = fmaxf(fmaxf(redM[rg][0][q], redM[rg][1][q]),
                           fmaxf(redM[rg][2][q], redM[rg][3][q]));

    float s = 0.f;
    #pragma unroll
    for (int ct = 0; ct < 16; ++ct)
        #pragma unroll
        for (int r = 0; r < 4; ++r) {
            float e = __expf(sv[ct][r] - mg);
            sv[ct][r] = e;
            s += e;
        }
    s += __shfl_xor(s, 16);
    s += __shfl_xor(s, 32);
    if (lane < 16) redS[rg][wk][lane] = s;
    __syncthreads();
    const float inv = 1.0f / (redS[rg][0][q] + redS[rg][1][q] + redS[rg][2][q] + redS[rg][3][q]);

    const unsigned sw = (unsigned)(q & 7) << 4;
    #pragma unroll
    for (int ct = 0; ct < 16; ++ct) {
        const int key0 = wk * 256 + ct * 16 + q4 * 4;
        ull pk = (ull)f2bf(sv[ct][0] * inv)
               | ((ull)f2bf(sv[ct][1] * inv) << 16)
               | ((ull)f2bf(sv[ct][2] * inv) << 32)
               | ((ull)f2bf(sv[ct][3] * inv) << 48);
        unsigned byte = (unsigned)(rg * 16 + q) * 2048u + (((unsigned)(key0 * 2)) ^ sw);
        *(ull*)((char*)P + byte) = pk;
    }
    __syncthreads();

    // V prefetch (2 kb-steps) before the store phase
    const char* vbase = (const char*)Vpack + ((size_t)bh << 17)
                      + (size_t)wk * 32 * 1024 + lane * 16;
    short8 v0a = *(const short8*)(vbase);
    short8 v1a = *(const short8*)(vbase + 1024);

    // coalesced nt attn store: wave w stores block-rows w*4..w*4+3 (1KB/instr)
    {
        const size_t aRow = ((size_t)bh * NQ_ + q0) * NK_;
        #pragma unroll
        for (int i = 0; i < 4; ++i) {
            const int r = w * 4 + i;
            const unsigned swr = (unsigned)(r & 7) << 4;
            #pragma unroll
            for (int j = 0; j < 4; ++j) {
                unsigned byte = (unsigned)r * 2048u
                              + (((unsigned)(j * 512 + lane * 8)) ^ swr);
                ull pk = *(const ull*)((const char*)P + byte);
                f32x4 o;
                o[0] = __builtin_bit_cast(float, (unsigned)((pk & 0xFFFFull) << 16));
                o[1] = __builtin_bit_cast(float, (unsigned)(((pk >> 16) & 0xFFFFull) << 16));
                o[2] = __builtin_bit_cast(float, (unsigned)(((pk >> 32) & 0xFFFFull) << 16));
                o[3] = __builtin_bit_cast(float, (unsigned)((pk >> 48) << 16));
                __builtin_nontemporal_store(o,
                    (f32x4*)&attnOut[aRow + (size_t)r * NK_ + j * 256 + lane * 4]);
            }
        }
    }

    // PV: rows of group rg x d-cols [16wk,16wk+16)
    f32x4 acc0 = {}, acc1 = {};
    const unsigned prow = (unsigned)(rg * 16 + q) * 2048u;
    #pragma unroll
    for (int kt = 0; kt < 16; ++kt) {
        short8 vb0 = v0a, vb1 = v1a;
        if (kt < 15) {
            v0a = *(const short8*)(vbase + (kt + 1) * 2048);
            v1a = *(const short8*)(vbase + (kt + 1) * 2048 + 1024);
        }
        const int kb = kt * 64;
        unsigned o0 = ((unsigned)((kb + q4 * 8) * 2)) ^ sw;
        unsigned o1 = ((unsigned)((kb + 32 + q4 * 8) * 2)) ^ sw;
        short8 pa0 = *(const short8*)((const char*)P + prow + o0);
        short8 pa1 = *(const short8*)((const char*)P + prow + o1);
        __builtin_amdgcn_s_setprio(1);
        acc0 = __builtin_amdgcn_mfma_f32_16x16x32_bf16(pa0, vb0, acc0, 0, 0, 0);
        acc1 = __builtin_amdgcn_mfma_f32_16x16x32_bf16(pa1, vb1, acc1, 0, 0, 0);
        __builtin_amdgcn_s_setprio(0);
    }
    #pragma unroll
    for (int r = 0; r < 4; ++r) {
        float o = acc0[r] + acc1[r];
        Ob[(size_t)(b * NQ_ + q0 + rg * 16 + q4 * 4 + r) * 512 + h * 64 + wk * 16 + q] = f2bf(o);
    }
}

// ---------------------------------------------------------------------------
extern "C" void kernel_launch(void* const* d_in, const int* in_sizes, int n_in,
                              void* d_out, int out_size, void* d_ws, size_t ws_size,
                              hipStream_t stream)
{
    (void)in_sizes; (void)n_in; (void)out_size; (void)ws_size;
    const float* x    = (const float*)d_in[0];
    const float* x_q  = (const float*)d_in[1];
    const float* w_q  = (const float*)d_in[2];
    const float* w_kv = (const float*)d_in[3];
    const float* w_p  = (const float*)d_in[4];
    const float* b_p  = (const float*)d_in[5];

    float* out   = (float*)d_out;
    float* attnO = out + (size_t)B_ * NQ_ * DM_;

    us* Wq_t  = (us*)d_ws;                  // 256K elems
    us* Wkv_t = Wq_t  + 262144;             // 512K
    us* Wp_t  = Wkv_t + 524288;             // 256K
    us* Qh    = Wp_t  + 262144;             // 2M
    us* Kp    = Qh    + 2097152;            // 2M
    us* Vp    = Kp    + 2097152;            // 2M
    us* Ob    = Vp    + 2097152;            // 2M  (~18.5 MB total)

    wprep<<<256, 256, 0, stream>>>(w_q, w_kv, w_p, Wq_t, Wkv_t, Wp_t);
    qkv128<<<dim3(4, 32, 3), 256, 0, stream>>>(x_q, x, Wq_t, Wkv_t, Qh, Kp, Vp);
    attn5<<<dim3(32, 8, 4), 512, 0, stream>>>(Qh, Kp, Vp, attnO, Ob);
    out128<<<dim3(4, 32), 256, 0, stream>>>(Ob, Wp_t, b_p, out);
}